// Round 1
// baseline (205.754 us; speedup 1.0000x reference)
//
#include <hip/hip_runtime.h>
#include <hip/hip_bf16.h>

#define NN 50000
#define NE 312500
#define FIN 256
#define KTOT 512
#define FOUT 256

typedef __attribute__((ext_vector_type(4))) float f32x4;
typedef __attribute__((ext_vector_type(8))) short bf16x8;

__global__ void k_zero(int* __restrict__ p, int n) {
  int i = blockIdx.x * 256 + threadIdx.x;
  if (i < n) p[i] = 0;
}

__global__ void k_hist(const int* __restrict__ Ai, int* __restrict__ deg) {
  int e = blockIdx.x * 256 + threadIdx.x;
  if (e < NE) atomicAdd(&deg[Ai[e]], 1);
}

// inclusive scan within blocks of 256; block sums out
__global__ void k_scan1(const int* __restrict__ deg, int* __restrict__ incl,
                        int* __restrict__ bsum) {
  __shared__ int sm[256];
  int i = blockIdx.x * 256 + threadIdx.x;
  int v = (i < NN) ? deg[i] : 0;
  sm[threadIdx.x] = v;
  __syncthreads();
  for (int s = 1; s < 256; s <<= 1) {
    int t = (threadIdx.x >= (unsigned)s) ? sm[threadIdx.x - s] : 0;
    __syncthreads();
    sm[threadIdx.x] += t;
    __syncthreads();
  }
  if (i < NN) incl[i] = sm[threadIdx.x];
  if (threadIdx.x == 255) bsum[blockIdx.x] = sm[255];
}

// exclusive scan of the 196 block sums (single block)
__global__ void k_scan2(int* __restrict__ bsum) {
  __shared__ int sm[256];
  int v = (threadIdx.x < 196) ? bsum[threadIdx.x] : 0;
  sm[threadIdx.x] = v;
  __syncthreads();
  for (int s = 1; s < 256; s <<= 1) {
    int t = (threadIdx.x >= (unsigned)s) ? sm[threadIdx.x - s] : 0;
    __syncthreads();
    sm[threadIdx.x] += t;
    __syncthreads();
  }
  if (threadIdx.x < 196) bsum[threadIdx.x] = sm[threadIdx.x] - v;
}

__global__ void k_scan3(const int* __restrict__ incl, const int* __restrict__ deg,
                        const int* __restrict__ bsum, int* __restrict__ offs,
                        int* __restrict__ cursor) {
  int i = blockIdx.x * 256 + threadIdx.x;
  if (i < NN) {
    int o = incl[i] - deg[i] + bsum[blockIdx.x];
    offs[i] = o;
    cursor[i] = o;
  }
}

__global__ void k_scatter(const int* __restrict__ Ai, const int* __restrict__ Aj,
                          int* __restrict__ cursor, int* __restrict__ edst) {
  int e = blockIdx.x * 256 + threadIdx.x;
  if (e < NE) {
    int p = atomicAdd(&cursor[Ai[e]], 1);
    edst[p] = Aj[e];
  }
}

__global__ void k_wconv(const float* __restrict__ W, unsigned short* __restrict__ Wb) {
  int i = blockIdx.x * 256 + threadIdx.x;
  if (i < FOUT * KTOT)
    Wb[i] = __builtin_bit_cast(unsigned short, __float2bfloat16(W[i]));
}

// one wave per node: S[n] = sum of x[Aj] over CSR neighbors (atomic-free)
__global__ __launch_bounds__(256) void k_gather(
    const float* __restrict__ x, const int* __restrict__ offs,
    const int* __restrict__ deg, const int* __restrict__ edst,
    float* __restrict__ S) {
  int wid = threadIdx.x >> 6;
  int lane = threadIdx.x & 63;
  int n = blockIdx.x * 4 + wid;
  if (n >= NN) return;
  int o = offs[n];
  int c = deg[n];
  f32x4 acc = {0.f, 0.f, 0.f, 0.f};
  const f32x4* xv = (const f32x4*)x;
  for (int e = 0; e < c; ++e) {
    int j = edst[o + e];
    acc += xv[(size_t)j * 64 + lane];
  }
  ((f32x4*)S)[(size_t)n * 64 + lane] = acc;
}

__device__ __forceinline__ bf16x8 cvt8(const float* p) {
  f32x4 a = *(const f32x4*)p;
  f32x4 c = *(const f32x4*)(p + 4);
  bf16x8 r;
  #pragma unroll
  for (int i = 0; i < 4; ++i) {
    r[i]     = (short)__builtin_bit_cast(unsigned short, __float2bfloat16(a[i]));
    r[i + 4] = (short)__builtin_bit_cast(unsigned short, __float2bfloat16(c[i]));
  }
  return r;
}

// out[n][o] = deg[n]*(x[n]@W1^T)[o] + (S[n]@W2^T)[o] + deg[n]*b[o]
// block: 64 rows x 256 cols; 4 waves as 2x2; wave: 32 rows x 128 cols
// S aliases out: each block reads only its own rows before writing them.
__global__ __launch_bounds__(256) void k_gemm(
    const float* __restrict__ x, const float* S, const unsigned short* __restrict__ Wb,
    const int* __restrict__ deg, const float* __restrict__ bias, float* out) {
  const int lane = threadIdx.x & 63;
  const int wid = threadIdx.x >> 6;
  const int wm = wid >> 1;
  const int wn = wid & 1;
  const int lr = lane & 15;   // A: row-in-frag, B: col-in-frag
  const int lk = lane >> 4;   // k sub-group
  const int n0 = blockIdx.x * 64;
  const int colbase = wn * 128;

  f32x4 acc[2][8];
  #pragma unroll
  for (int m = 0; m < 2; ++m)
    #pragma unroll
    for (int n = 0; n < 8; ++n) acc[m][n] = (f32x4){0.f, 0.f, 0.f, 0.f};

  int rowA[2];
  #pragma unroll
  for (int m = 0; m < 2; ++m) {
    int r = n0 + wm * 32 + m * 16 + lr;
    rowA[m] = (r < NN) ? r : (NN - 1);
  }

  // Phase 1: A = x, k in [0,256)
  #pragma unroll
  for (int kk = 0; kk < 8; ++kk) {
    bf16x8 afr[2];
    #pragma unroll
    for (int m = 0; m < 2; ++m)
      afr[m] = cvt8(x + (size_t)rowA[m] * FIN + kk * 32 + lk * 8);
    #pragma unroll
    for (int n = 0; n < 8; ++n) {
      int col = colbase + n * 16 + lr;
      bf16x8 bfr = *(const bf16x8*)(Wb + (size_t)col * KTOT + kk * 32 + lk * 8);
      #pragma unroll
      for (int m = 0; m < 2; ++m)
        acc[m][n] = __builtin_amdgcn_mfma_f32_16x16x32_bf16(afr[m], bfr, acc[m][n], 0, 0, 0);
    }
  }

  // scale phase-1 accumulators by deg (keeps deg*x in fp32 precision)
  float dg[2][4];
  #pragma unroll
  for (int m = 0; m < 2; ++m)
    #pragma unroll
    for (int r = 0; r < 4; ++r) {
      int row = n0 + wm * 32 + m * 16 + lk * 4 + r;  // < 50048 (zero-padded alloc)
      dg[m][r] = (float)deg[row];
    }
  #pragma unroll
  for (int m = 0; m < 2; ++m)
    #pragma unroll
    for (int n = 0; n < 8; ++n)
      #pragma unroll
      for (int r = 0; r < 4; ++r)
        acc[m][n][r] *= dg[m][r];

  // Phase 2: A = S, k in [256,512)
  #pragma unroll
  for (int kk = 0; kk < 8; ++kk) {
    bf16x8 afr[2];
    #pragma unroll
    for (int m = 0; m < 2; ++m)
      afr[m] = cvt8(S + (size_t)rowA[m] * FIN + kk * 32 + lk * 8);
    #pragma unroll
    for (int n = 0; n < 8; ++n) {
      int col = colbase + n * 16 + lr;
      bf16x8 bfr = *(const bf16x8*)(Wb + (size_t)col * KTOT + 256 + kk * 32 + lk * 8);
      #pragma unroll
      for (int m = 0; m < 2; ++m)
        acc[m][n] = __builtin_amdgcn_mfma_f32_16x16x32_bf16(afr[m], bfr, acc[m][n], 0, 0, 0);
    }
  }

  // epilogue: + deg*b, guarded store
  #pragma unroll
  for (int n = 0; n < 8; ++n) {
    int col = colbase + n * 16 + lr;
    float bv = bias[col];
    #pragma unroll
    for (int m = 0; m < 2; ++m) {
      #pragma unroll
      for (int r = 0; r < 4; ++r) {
        int row = n0 + wm * 32 + m * 16 + lk * 4 + r;
        if (row < NN) out[(size_t)row * FOUT + col] = acc[m][n][r] + dg[m][r] * bv;
      }
    }
  }
}

extern "C" void kernel_launch(void* const* d_in, const int* in_sizes, int n_in,
                              void* d_out, int out_size, void* d_ws, size_t ws_size,
                              hipStream_t stream) {
  const float* x = (const float*)d_in[0];
  const float* W = (const float*)d_in[1];
  const float* b = (const float*)d_in[2];
  const int* Ai = (const int*)d_in[3];
  const int* Aj = (const int*)d_in[4];
  float* out = (float*)d_out;

  int* ip = (int*)d_ws;
  int* deg    = ip;            // 50048 ints (zero-padded)
  int* incl   = ip + 50048;
  int* offs   = ip + 100096;
  int* cursor = ip + 150144;
  int* bsum   = ip + 200192;   // 256 ints
  int* edst   = ip + 200448;   // 312576 ints
  unsigned short* Wb = (unsigned short*)(ip + 513024);  // 131072 bf16 (~2.3MB total ws)

  k_zero<<<196, 256, 0, stream>>>(deg, 50048);
  k_hist<<<1221, 256, 0, stream>>>(Ai, deg);
  k_scan1<<<196, 256, 0, stream>>>(deg, incl, bsum);
  k_scan2<<<1, 256, 0, stream>>>(bsum);
  k_scan3<<<196, 256, 0, stream>>>(incl, deg, bsum, offs, cursor);
  k_scatter<<<1221, 256, 0, stream>>>(Ai, Aj, cursor, edst);
  k_wconv<<<512, 256, 0, stream>>>(W, Wb);
  k_gather<<<12500, 256, 0, stream>>>(x, offs, deg, edst, out);
  k_gemm<<<782, 256, 0, stream>>>(x, out, Wb, deg, b, out);
}

// Round 2
// 167.081 us; speedup vs baseline: 1.2315x; 1.2315x over previous
//
#include <hip/hip_runtime.h>
#include <hip/hip_bf16.h>

#define NN 50000
#define NE 312500
#define FIN 256
#define FOUT 256

typedef __attribute__((ext_vector_type(4))) float f32x4;
typedef __attribute__((ext_vector_type(8))) short bf16x8;
typedef __attribute__((ext_vector_type(4))) unsigned short u16x4;

__global__ void k_zero(int* __restrict__ p, int n) {
  int i = blockIdx.x * 256 + threadIdx.x;
  if (i < n) p[i] = 0;
}

__global__ void k_hist(const int* __restrict__ Ai, int* __restrict__ deg) {
  int e = blockIdx.x * 256 + threadIdx.x;
  if (e < NE) atomicAdd(&deg[Ai[e]], 1);
}

__global__ void k_scan1(const int* __restrict__ deg, int* __restrict__ incl,
                        int* __restrict__ bsum) {
  __shared__ int sm[256];
  int i = blockIdx.x * 256 + threadIdx.x;
  int v = (i < NN) ? deg[i] : 0;
  sm[threadIdx.x] = v;
  __syncthreads();
  for (int s = 1; s < 256; s <<= 1) {
    int t = (threadIdx.x >= (unsigned)s) ? sm[threadIdx.x - s] : 0;
    __syncthreads();
    sm[threadIdx.x] += t;
    __syncthreads();
  }
  if (i < NN) incl[i] = sm[threadIdx.x];
  if (threadIdx.x == 255) bsum[blockIdx.x] = sm[255];
}

__global__ void k_scan2(int* __restrict__ bsum) {
  __shared__ int sm[256];
  int v = (threadIdx.x < 196) ? bsum[threadIdx.x] : 0;
  sm[threadIdx.x] = v;
  __syncthreads();
  for (int s = 1; s < 256; s <<= 1) {
    int t = (threadIdx.x >= (unsigned)s) ? sm[threadIdx.x - s] : 0;
    __syncthreads();
    sm[threadIdx.x] += t;
    __syncthreads();
  }
  if (threadIdx.x < 196) bsum[threadIdx.x] = sm[threadIdx.x] - v;
}

__global__ void k_scan3(const int* __restrict__ incl, const int* __restrict__ deg,
                        const int* __restrict__ bsum, int* __restrict__ offs,
                        int* __restrict__ cursor) {
  int i = blockIdx.x * 256 + threadIdx.x;
  if (i < NN) {
    int o = incl[i] - deg[i] + bsum[blockIdx.x];
    offs[i] = o;
    cursor[i] = o;
  }
}

__global__ void k_scatter(const int* __restrict__ Ai, const int* __restrict__ Aj,
                          int* __restrict__ cursor, int* __restrict__ edst) {
  int e = blockIdx.x * 256 + threadIdx.x;
  if (e < NE) {
    int p = atomicAdd(&cursor[Ai[e]], 1);
    edst[p] = Aj[e];
  }
}

// Pack Wcat[o][k] (o in [0,512): o<256 -> W1 row o, else W2 row o-256; k in [0,256))
// into MFMA B-fragment order: chunk c = (o/16)*8 + kk holds 512 bf16 laid out so
// lane l = (k_sub<<4)|(o&15) reads its 8 elems at byte l*16 -> 1KB coalesced loads.
__global__ __launch_bounds__(256) void k_wconv(const float* __restrict__ W,
                                               unsigned short* __restrict__ WbP) {
  int lane = threadIdx.x & 63, wid = threadIdx.x >> 6;
  int c = blockIdx.x * 4 + wid;           // 256 chunks
  int o16 = c >> 3, kk = c & 7;
  int lr = lane & 15, lk = lane >> 4;
  int o = o16 * 16 + lr;
  int k = kk * 32 + lk * 8;
  const float* src = (o < 256) ? (W + (size_t)o * 512 + k)
                               : (W + (size_t)(o - 256) * 512 + 256 + k);
  unsigned short* dst = WbP + (size_t)c * 512 + lane * 8;
  #pragma unroll
  for (int i = 0; i < 8; ++i)
    dst[i] = __builtin_bit_cast(unsigned short, __float2bfloat16(src[i]));
}

__device__ __forceinline__ bf16x8 cvt8(const float* p) {
  f32x4 a = *(const f32x4*)p;
  f32x4 c = *(const f32x4*)(p + 4);
  bf16x8 r;
  #pragma unroll
  for (int i = 0; i < 4; ++i) {
    r[i]     = (short)__builtin_bit_cast(unsigned short, __float2bfloat16(a[i]));
    r[i + 4] = (short)__builtin_bit_cast(unsigned short, __float2bfloat16(c[i]));
  }
  return r;
}

// Y = x @ [W1 | W2]^T. Block: 64 rows x 256 cols of one half h.
// h==0: out[row][col] = deg[row]*(acc + b[col])   (fp32, final Y1 contribution)
// h==1: Y2b[row][col] = bf16(acc)                 (consumed by k_epi gather)
__global__ __launch_bounds__(256) void k_gemmY(
    const float* __restrict__ x, const unsigned short* __restrict__ WbP,
    const int* __restrict__ deg, const float* __restrict__ bias,
    float* __restrict__ out, unsigned short* __restrict__ Y2b) {
  const int lane = threadIdx.x & 63;
  const int wid = threadIdx.x >> 6;
  const int wm = wid >> 1;
  const int wn = wid & 1;
  const int lr = lane & 15;
  const int lk = lane >> 4;
  const int n0 = blockIdx.x * 64;
  const int h = blockIdx.y;
  const int o16base = h * 16 + wn * 8;

  f32x4 acc[2][8];
  #pragma unroll
  for (int m = 0; m < 2; ++m)
    #pragma unroll
    for (int n = 0; n < 8; ++n) acc[m][n] = (f32x4){0.f, 0.f, 0.f, 0.f};

  int rowA[2];
  #pragma unroll
  for (int m = 0; m < 2; ++m) {
    int r = n0 + wm * 32 + m * 16 + lr;
    rowA[m] = (r < NN) ? r : (NN - 1);
  }

  #pragma unroll
  for (int kk = 0; kk < 8; ++kk) {
    bf16x8 afr[2];
    #pragma unroll
    for (int m = 0; m < 2; ++m)
      afr[m] = cvt8(x + (size_t)rowA[m] * FIN + kk * 32 + lk * 8);
    #pragma unroll
    for (int n = 0; n < 8; ++n) {
      bf16x8 bfr = *(const bf16x8*)(WbP + ((size_t)(o16base + n) * 8 + kk) * 512 + lane * 8);
      #pragma unroll
      for (int m = 0; m < 2; ++m)
        acc[m][n] = __builtin_amdgcn_mfma_f32_16x16x32_bf16(afr[m], bfr, acc[m][n], 0, 0, 0);
    }
  }

  if (h == 0) {
    float dg[2][4];
    #pragma unroll
    for (int m = 0; m < 2; ++m)
      #pragma unroll
      for (int r = 0; r < 4; ++r)
        dg[m][r] = (float)deg[n0 + wm * 32 + m * 16 + lk * 4 + r];  // deg padded to 50048
    #pragma unroll
    for (int n = 0; n < 8; ++n) {
      int col = wn * 128 + n * 16 + lr;
      float bv = bias[col];
      #pragma unroll
      for (int m = 0; m < 2; ++m)
        #pragma unroll
        for (int r = 0; r < 4; ++r) {
          int row = n0 + wm * 32 + m * 16 + lk * 4 + r;
          if (row < NN)
            out[(size_t)row * FOUT + col] = dg[m][r] * (acc[m][n][r] + bv);
        }
    }
  } else {
    #pragma unroll
    for (int n = 0; n < 8; ++n) {
      int col = wn * 128 + n * 16 + lr;
      #pragma unroll
      for (int m = 0; m < 2; ++m)
        #pragma unroll
        for (int r = 0; r < 4; ++r) {
          int row = n0 + wm * 32 + m * 16 + lk * 4 + r;
          if (row < NN)
            Y2b[(size_t)row * FOUT + col] =
                __builtin_bit_cast(unsigned short, __float2bfloat16(acc[m][n][r]));
        }
    }
  }
}

// One wave per node: out[n] += sum over CSR neighbors of Y2b[j] (512B rows, coalesced)
__global__ __launch_bounds__(256) void k_epi(
    const unsigned short* __restrict__ Y2b, const int* __restrict__ offs,
    const int* __restrict__ deg, const int* __restrict__ edst,
    float* __restrict__ out) {
  int wid = threadIdx.x >> 6;
  int lane = threadIdx.x & 63;
  int n = blockIdx.x * 4 + wid;
  if (n >= NN) return;
  int o = offs[n];
  int c = deg[n];
  f32x4 acc = {0.f, 0.f, 0.f, 0.f};
  for (int e = 0; e < c; ++e) {
    int j = edst[o + e];
    u16x4 v = *(const u16x4*)(Y2b + (size_t)j * FOUT + lane * 4);
    #pragma unroll
    for (int i = 0; i < 4; ++i)
      acc[i] += __builtin_bit_cast(float, ((unsigned int)v[i]) << 16);
  }
  f32x4* ov = (f32x4*)out + (size_t)n * 64 + lane;
  *ov += acc;
}

extern "C" void kernel_launch(void* const* d_in, const int* in_sizes, int n_in,
                              void* d_out, int out_size, void* d_ws, size_t ws_size,
                              hipStream_t stream) {
  const float* x = (const float*)d_in[0];
  const float* W = (const float*)d_in[1];
  const float* b = (const float*)d_in[2];
  const int* Ai = (const int*)d_in[3];
  const int* Aj = (const int*)d_in[4];
  float* out = (float*)d_out;

  int* ip = (int*)d_ws;
  int* deg    = ip;            // 50048 (zero-padded; max gemm row index = 50047)
  int* incl   = ip + 50048;
  int* offs   = ip + 100096;
  int* cursor = ip + 150144;
  int* bsum   = ip + 200192;   // 256
  int* edst   = ip + 200448;   // 312576
  unsigned short* WbP = (unsigned short*)(ip + 513024);   // 131072 bf16 = 256KB
  unsigned short* Y2b = (unsigned short*)(ip + 578560);   // 12.8M bf16 = 25.6MB

  k_zero<<<196, 256, 0, stream>>>(deg, 50048);
  k_hist<<<1221, 256, 0, stream>>>(Ai, deg);
  k_scan1<<<196, 256, 0, stream>>>(deg, incl, bsum);
  k_scan2<<<1, 256, 0, stream>>>(bsum);
  k_scan3<<<196, 256, 0, stream>>>(incl, deg, bsum, offs, cursor);
  k_scatter<<<1221, 256, 0, stream>>>(Ai, Aj, cursor, edst);
  k_wconv<<<64, 256, 0, stream>>>(W, WbP);
  k_gemmY<<<dim3(782, 2), 256, 0, stream>>>(x, WbP, deg, b, out, Y2b);
  k_epi<<<12500, 256, 0, stream>>>(Y2b, offs, deg, edst, out);
}

// Round 4
// 163.779 us; speedup vs baseline: 1.2563x; 1.0202x over previous
//
#include <hip/hip_runtime.h>
#include <hip/hip_bf16.h>

#define NN 50000
#define NE 312500
#define FIN 256
#define FOUT 256
#define MPAD 50048   // 391*128

typedef __attribute__((ext_vector_type(4))) float f32x4;
typedef __attribute__((ext_vector_type(8))) short bf16x8;
typedef __attribute__((ext_vector_type(4))) unsigned short u16x4;

__global__ void k_zero(int* __restrict__ p, int n) {
  int i = blockIdx.x * 256 + threadIdx.x;
  if (i < n) p[i] = 0;
}

__global__ void k_hist(const int* __restrict__ Ai, int* __restrict__ deg) {
  int e = blockIdx.x * 256 + threadIdx.x;
  if (e < NE) atomicAdd(&deg[Ai[e]], 1);
}

__global__ void k_scan1(const int* __restrict__ deg, int* __restrict__ incl,
                        int* __restrict__ bsum) {
  __shared__ int sm[256];
  int i = blockIdx.x * 256 + threadIdx.x;
  int v = (i < NN) ? deg[i] : 0;
  sm[threadIdx.x] = v;
  __syncthreads();
  for (int s = 1; s < 256; s <<= 1) {
    int t = (threadIdx.x >= (unsigned)s) ? sm[threadIdx.x - s] : 0;
    __syncthreads();
    sm[threadIdx.x] += t;
    __syncthreads();
  }
  if (i < NN) incl[i] = sm[threadIdx.x];
  if (threadIdx.x == 255) bsum[blockIdx.x] = sm[255];
}

__global__ void k_scan2(int* __restrict__ bsum) {
  __shared__ int sm[256];
  int v = (threadIdx.x < 196) ? bsum[threadIdx.x] : 0;
  sm[threadIdx.x] = v;
  __syncthreads();
  for (int s = 1; s < 256; s <<= 1) {
    int t = (threadIdx.x >= (unsigned)s) ? sm[threadIdx.x - s] : 0;
    __syncthreads();
    sm[threadIdx.x] += t;
    __syncthreads();
  }
  if (threadIdx.x < 196) bsum[threadIdx.x] = sm[threadIdx.x] - v;
}

__global__ void k_scan3(const int* __restrict__ incl, const int* __restrict__ deg,
                        const int* __restrict__ bsum, int* __restrict__ offs,
                        int* __restrict__ cursor) {
  int i = blockIdx.x * 256 + threadIdx.x;
  if (i < NN) {
    int o = incl[i] - deg[i] + bsum[blockIdx.x];
    offs[i] = o;
    cursor[i] = o;
  }
}

__global__ void k_scatter(const int* __restrict__ Ai, const int* __restrict__ Aj,
                          int* __restrict__ cursor, int* __restrict__ edst) {
  int e = blockIdx.x * 256 + threadIdx.x;
  if (e < NE) {
    int p = atomicAdd(&cursor[Ai[e]], 1);
    edst[p] = Aj[e];
  }
}

__device__ __forceinline__ bf16x8 cvt8(const float* p) {
  f32x4 a = *(const f32x4*)p;
  f32x4 c = *(const f32x4*)(p + 4);
  bf16x8 r;
  #pragma unroll
  for (int i = 0; i < 4; ++i) {
    r[i]     = (short)__builtin_bit_cast(unsigned short, __float2bfloat16(a[i]));
    r[i + 4] = (short)__builtin_bit_cast(unsigned short, __float2bfloat16(c[i]));
  }
  return r;
}

// Pack Wcat[o][k] (o<256 -> W1 row o; o>=256 -> W2 row o-256) into B-fragment
// order: chunk c = (o/16)*8 + kk, lane l=(lk<<4)|lr holds 8 bf16 of
// (col o16*16+lr, k kk*32+lk*8). 1KB contiguous per chunk.
__global__ __launch_bounds__(256) void k_wconv(const float* __restrict__ W,
                                               unsigned short* __restrict__ WbP) {
  int lane = threadIdx.x & 63, wid = threadIdx.x >> 6;
  int c = blockIdx.x * 4 + wid;           // 256 chunks
  int o16 = c >> 3, kk = c & 7;
  int lr = lane & 15, lk = lane >> 4;
  int o = o16 * 16 + lr;
  int k = kk * 32 + lk * 8;
  const float* src = (o < 256) ? (W + (size_t)o * 512 + k)
                               : (W + (size_t)(o - 256) * 512 + 256 + k);
  *(bf16x8*)(WbP + (size_t)c * 512 + lane * 8) = cvt8(src);
}

// x (fp32 row-major) -> xbP (bf16, A-fragment order), rows padded to MPAD with 0.
// chunk c = row16*8 + kk (row16 in [0,3128)); lane l: row=row16*16+(l&15),
// k=kk*32+(l>>4)*8. Writes fully coalesced 16B/lane.
__global__ __launch_bounds__(256) void k_xconv(const float* __restrict__ x,
                                               unsigned short* __restrict__ xbP) {
  int lane = threadIdx.x & 63;
  int c = blockIdx.x * 4 + (threadIdx.x >> 6);   // 25024 chunks
  int row = (c >> 3) * 16 + (lane & 15);
  int k0 = (c & 7) * 32 + (lane >> 4) * 8;
  bf16x8 v = {0, 0, 0, 0, 0, 0, 0, 0};
  if (row < NN) v = cvt8(x + (size_t)row * FIN + k0);
  *(bf16x8*)(xbP + (size_t)c * 512 + lane * 8) = v;
}

// Y = x @ [W1|W2]^T via fragment-ordered operands, no LDS, reg double-buffer.
// Grid (391, 4): 128-row x 128-col tile; quadrant q: cols q*128..+127 of 512.
// q<2 -> out[row][col] = deg*(acc+b); q>=2 -> Y2b[row][col-256] = bf16(acc).
__global__ __launch_bounds__(256) void k_gemmY(
    const unsigned short* __restrict__ xbP, const unsigned short* __restrict__ WbP,
    const int* __restrict__ deg, const float* __restrict__ bias,
    float* __restrict__ out, unsigned short* __restrict__ Y2b) {
  const int lane = threadIdx.x & 63;
  const int wid = threadIdx.x >> 6;
  const int wm = wid >> 1, wn = wid & 1;
  const int lr = lane & 15, lk = lane >> 4;
  const int q = blockIdx.y;
  const int rt0 = blockIdx.x * 8 + wm * 4;     // row16 base (4 m-frags)
  const int ct0 = q * 8 + wn * 4;              // col16 base (4 n-frags)

  f32x4 acc[4][4];
  #pragma unroll
  for (int m = 0; m < 4; ++m)
    #pragma unroll
    for (int n = 0; n < 4; ++n) acc[m][n] = (f32x4){0.f, 0.f, 0.f, 0.f};

  bf16x8 af[2][4], bf[2][4];
  #pragma unroll
  for (int i = 0; i < 4; ++i) {
    af[0][i] = *(const bf16x8*)(xbP + ((size_t)(rt0 + i) * 8 + 0) * 512 + lane * 8);
    bf[0][i] = *(const bf16x8*)(WbP + ((size_t)(ct0 + i) * 8 + 0) * 512 + lane * 8);
  }

  #pragma unroll
  for (int kk = 0; kk < 8; ++kk) {
    const int cur = kk & 1, nxt = cur ^ 1;
    if (kk < 7) {
      #pragma unroll
      for (int i = 0; i < 4; ++i) {
        af[nxt][i] = *(const bf16x8*)(xbP + ((size_t)(rt0 + i) * 8 + kk + 1) * 512 + lane * 8);
        bf[nxt][i] = *(const bf16x8*)(WbP + ((size_t)(ct0 + i) * 8 + kk + 1) * 512 + lane * 8);
      }
    }
    #pragma unroll
    for (int m = 0; m < 4; ++m)
      #pragma unroll
      for (int n = 0; n < 4; ++n)
        acc[m][n] = __builtin_amdgcn_mfma_f32_16x16x32_bf16(af[cur][m], bf[cur][n], acc[m][n], 0, 0, 0);
  }

  if (q < 2) {
    float dg[4][4];
    #pragma unroll
    for (int m = 0; m < 4; ++m)
      #pragma unroll
      for (int r = 0; r < 4; ++r)
        dg[m][r] = (float)deg[(rt0 + m) * 16 + lk * 4 + r];   // deg padded to MPAD
    #pragma unroll
    for (int n = 0; n < 4; ++n) {
      int col = (ct0 + n) * 16 + lr;
      float bv = bias[col];
      #pragma unroll
      for (int m = 0; m < 4; ++m)
        #pragma unroll
        for (int r = 0; r < 4; ++r) {
          int row = (rt0 + m) * 16 + lk * 4 + r;
          if (row < NN)
            out[(size_t)row * FOUT + col] = dg[m][r] * (acc[m][n][r] + bv);
        }
    }
  } else {
    #pragma unroll
    for (int n = 0; n < 4; ++n) {
      int col = (ct0 + n) * 16 + lr - 256;
      #pragma unroll
      for (int m = 0; m < 4; ++m)
        #pragma unroll
        for (int r = 0; r < 4; ++r) {
          int row = (rt0 + m) * 16 + lk * 4 + r;
          if (row < NN)
            Y2b[(size_t)row * FOUT + col] =
                __builtin_bit_cast(unsigned short, __float2bfloat16(acc[m][n][r]));
        }
    }
  }
}

// One wave per node: out[n] += sum over CSR neighbors of Y2b[j] (512B rows)
__global__ __launch_bounds__(256) void k_epi(
    const unsigned short* __restrict__ Y2b, const int* __restrict__ offs,
    const int* __restrict__ deg, const int* __restrict__ edst,
    float* __restrict__ out) {
  int wid = threadIdx.x >> 6;
  int lane = threadIdx.x & 63;
  int n = blockIdx.x * 4 + wid;
  if (n >= NN) return;
  int o = offs[n];
  int c = deg[n];
  f32x4 acc = {0.f, 0.f, 0.f, 0.f};
  for (int e = 0; e < c; ++e) {
    int j = edst[o + e];
    u16x4 v = *(const u16x4*)(Y2b + (size_t)j * FOUT + lane * 4);
    #pragma unroll
    for (int i = 0; i < 4; ++i)
      acc[i] += __builtin_bit_cast(float, ((unsigned int)v[i]) << 16);
  }
  f32x4* ov = (f32x4*)out + (size_t)n * 64 + lane;
  *ov += acc;
}

extern "C" void kernel_launch(void* const* d_in, const int* in_sizes, int n_in,
                              void* d_out, int out_size, void* d_ws, size_t ws_size,
                              hipStream_t stream) {
  const float* x = (const float*)d_in[0];
  const float* W = (const float*)d_in[1];
  const float* b = (const float*)d_in[2];
  const int* Ai = (const int*)d_in[3];
  const int* Aj = (const int*)d_in[4];
  float* out = (float*)d_out;

  int* ip = (int*)d_ws;
  int* deg    = ip;            // 50048 (zeroed, padded)
  int* incl   = ip + 50048;
  int* offs   = ip + 100096;
  int* cursor = ip + 150144;
  int* bsum   = ip + 200192;   // 256
  int* edst   = ip + 200448;   // 312576
  unsigned short* WbP = (unsigned short*)(ip + 513024);      // 256KB
  unsigned short* Y2b = (unsigned short*)(ip + 578560);      // 25.6MB
  unsigned short* xbP = (unsigned short*)(ip + 6984704);     // 25.6MB  (~53.6MB total)

  k_zero<<<196, 256, 0, stream>>>(deg, 50048);
  k_hist<<<1221, 256, 0, stream>>>(Ai, deg);
  k_scan1<<<196, 256, 0, stream>>>(deg, incl, bsum);
  k_scan2<<<1, 256, 0, stream>>>(bsum);
  k_scan3<<<196, 256, 0, stream>>>(incl, deg, bsum, offs, cursor);
  k_scatter<<<1221, 256, 0, stream>>>(Ai, Aj, cursor, edst);
  k_wconv<<<64, 256, 0, stream>>>(W, WbP);
  k_xconv<<<6256, 256, 0, stream>>>(x, xbP);
  k_gemmY<<<dim3(391, 4), 256, 0, stream>>>(xbP, WbP, deg, b, out, Y2b);
  k_epi<<<12500, 256, 0, stream>>>(Y2b, offs, deg, edst, out);
}

// Round 5
// 126.232 us; speedup vs baseline: 1.6300x; 1.2974x over previous
//
#include <hip/hip_runtime.h>
#include <hip/hip_bf16.h>

#define NN 50000
#define NE 312500
#define FIN 256
#define MPAD 50048   // 782*64

typedef __attribute__((ext_vector_type(4))) float f32x4;
typedef __attribute__((ext_vector_type(8))) short bf16x8;
typedef __attribute__((ext_vector_type(4))) unsigned short u16x4;

__global__ void k_hist(const int* __restrict__ Ai, int* __restrict__ deg) {
  int e = blockIdx.x * 256 + threadIdx.x;
  if (e < NE) atomicAdd(&deg[Ai[e]], 1);
}

__global__ void k_scan1(const int* __restrict__ deg, int* __restrict__ incl,
                        int* __restrict__ bsum) {
  __shared__ int sm[256];
  int i = blockIdx.x * 256 + threadIdx.x;
  int v = (i < NN) ? deg[i] : 0;
  sm[threadIdx.x] = v;
  __syncthreads();
  for (int s = 1; s < 256; s <<= 1) {
    int t = (threadIdx.x >= (unsigned)s) ? sm[threadIdx.x - s] : 0;
    __syncthreads();
    sm[threadIdx.x] += t;
    __syncthreads();
  }
  if (i < NN) incl[i] = sm[threadIdx.x];
  if (threadIdx.x == 255) bsum[blockIdx.x] = sm[255];
}

__global__ void k_scan2(int* __restrict__ bsum) {
  __shared__ int sm[256];
  int v = (threadIdx.x < 196) ? bsum[threadIdx.x] : 0;
  sm[threadIdx.x] = v;
  __syncthreads();
  for (int s = 1; s < 256; s <<= 1) {
    int t = (threadIdx.x >= (unsigned)s) ? sm[threadIdx.x - s] : 0;
    __syncthreads();
    sm[threadIdx.x] += t;
    __syncthreads();
  }
  if (threadIdx.x < 196) bsum[threadIdx.x] = sm[threadIdx.x] - v;
}

__global__ void k_scan3(const int* __restrict__ incl, const int* __restrict__ deg,
                        const int* __restrict__ bsum, int* __restrict__ offs,
                        int* __restrict__ cursor) {
  int i = blockIdx.x * 256 + threadIdx.x;
  if (i < NN) {
    int o = incl[i] - deg[i] + bsum[blockIdx.x];
    offs[i] = o;
    cursor[i] = o;
  }
}

__global__ void k_scatter(const int* __restrict__ Ai, const int* __restrict__ Aj,
                          int* __restrict__ cursor, int* __restrict__ edst) {
  int e = blockIdx.x * 256 + threadIdx.x;
  if (e < NE) {
    int p = atomicAdd(&cursor[Ai[e]], 1);
    edst[p] = Aj[e];
  }
}

__device__ __forceinline__ bf16x8 cvt8(const float* p) {
  f32x4 a = *(const f32x4*)p;
  f32x4 c = *(const f32x4*)(p + 4);
  bf16x8 r;
  #pragma unroll
  for (int i = 0; i < 4; ++i) {
    r[i]     = (short)__builtin_bit_cast(unsigned short, __float2bfloat16(a[i]));
    r[i + 4] = (short)__builtin_bit_cast(unsigned short, __float2bfloat16(c[i]));
  }
  return r;
}

// Pack Wcat[o][k] (o<256 -> W1 row o; o>=256 -> W2 row o-256) into B-fragment
// order: chunk c = (o/16)*8 + kk; lane l=(lk<<4)|lr holds 8 bf16 of
// (col o16*16+lr, k kk*32+lk*8). 1KB contiguous per chunk.
__global__ __launch_bounds__(256) void k_wconv(const float* __restrict__ W,
                                               unsigned short* __restrict__ WbP) {
  int lane = threadIdx.x & 63, wid = threadIdx.x >> 6;
  int c = blockIdx.x * 4 + wid;           // 256 chunks
  int o16 = c >> 3, kk = c & 7;
  int lr = lane & 15, lk = lane >> 4;
  int o = o16 * 16 + lr;
  int k = kk * 32 + lk * 8;
  const float* src = (o < 256) ? (W + (size_t)o * 512 + k)
                               : (W + (size_t)(o - 256) * 512 + 256 + k);
  *(bf16x8*)(WbP + (size_t)c * 512 + lane * 8) = cvt8(src);
}

// Fused GEMM: Yb[row][0..511] = bf16( x[row] @ [W1|W2]^T ).
// Block: 64 rows x 512 cols; 4 waves, wave w = cols w*128..+127 (8 col16 frags).
// x staged fp32->bf16 A-fragments in LDS once; reg ping-pong over 8 K-steps;
// epilogue transposes 16x128 chunks through XOR-swizzled LDS -> 16B stores.
__global__ __launch_bounds__(256, 2) void k_gemm(
    const float* __restrict__ x, const unsigned short* __restrict__ WbP,
    unsigned short* __restrict__ Yb) {
  __shared__ unsigned short Alds[16384];   // 32 KB: 32 chunks x 512 bf16
  const int tid = threadIdx.x;
  const int lane = tid & 63, wid = tid >> 6;
  const int lr = lane & 15, lk = lane >> 4;
  const int n0 = blockIdx.x * 64;

  // ---- stage A: 64 rows x 256 k, fragment order ----
  #pragma unroll
  for (int it = 0; it < 8; ++it) {
    int i = it * 256 + tid;          // 0..2047
    int row = i >> 5, seg = i & 31;  // seg = 8-float group
    int g = n0 + row;
    bf16x8 v = {0, 0, 0, 0, 0, 0, 0, 0};
    if (g < NN) v = cvt8(x + (size_t)g * FIN + seg * 8);
    int kk = seg >> 2, lkk = seg & 3;
    int chunk = (row >> 4) * 8 + kk;
    *(bf16x8*)(Alds + chunk * 512 + (lkk * 16 + (row & 15)) * 8) = v;
  }
  __syncthreads();

  f32x4 acc[4][8];
  #pragma unroll
  for (int m = 0; m < 4; ++m)
    #pragma unroll
    for (int n = 0; n < 8; ++n) acc[m][n] = (f32x4){0.f, 0.f, 0.f, 0.f};

  bf16x8 af[2][4], bfr[2][8];
  #pragma unroll
  for (int m = 0; m < 4; ++m)
    af[0][m] = *(const bf16x8*)(Alds + (m * 8 + 0) * 512 + lane * 8);
  #pragma unroll
  for (int n = 0; n < 8; ++n)
    bfr[0][n] = *(const bf16x8*)(WbP + ((size_t)((wid * 8 + n) * 8 + 0)) * 512 + lane * 8);

  #pragma unroll
  for (int kk = 0; kk < 8; ++kk) {
    const int cur = kk & 1, nxt = cur ^ 1;
    if (kk < 7) {
      #pragma unroll
      for (int m = 0; m < 4; ++m)
        af[nxt][m] = *(const bf16x8*)(Alds + (m * 8 + kk + 1) * 512 + lane * 8);
      #pragma unroll
      for (int n = 0; n < 8; ++n)
        bfr[nxt][n] = *(const bf16x8*)(WbP + ((size_t)((wid * 8 + n) * 8 + kk + 1)) * 512 + lane * 8);
    }
    #pragma unroll
    for (int m = 0; m < 4; ++m)
      #pragma unroll
      for (int n = 0; n < 8; ++n)
        acc[m][n] = __builtin_amdgcn_mfma_f32_16x16x32_bf16(af[cur][m], bfr[cur][n], acc[m][n], 0, 0, 0);
  }

  __syncthreads();   // A-tile no longer needed; LDS reused per-wave below

  // ---- epilogue: per m-chunk (16 rows x 128 cols), LDS transpose, 16B stores ----
  // per-wave region: 2 x 2048 u16 ping-pong (wid*4096 .. +4095)
  #pragma unroll
  for (int m = 0; m < 4; ++m) {
    unsigned short* R = Alds + wid * 4096 + (m & 1) * 2048;
    #pragma unroll
    for (int n = 0; n < 8; ++n) {
      #pragma unroll
      for (int r = 0; r < 4; ++r) {
        int col = n * 16 + lr;
        int word = (lk * 4 + r) * 64 + (((unsigned)col >> 1) ^ (lk << 3));
        R[word * 2 + (col & 1)] =
            __builtin_bit_cast(unsigned short, __float2bfloat16(acc[m][n][r]));
      }
    }
    #pragma unroll
    for (int p = 0; p < 4; ++p) {
      int row_l = p * 4 + lk;
      bf16x8 v = *(const bf16x8*)(R + (row_l * 64 + ((lr * 4) ^ (p << 3))) * 2);
      int rowg = n0 + m * 16 + row_l;
      if (rowg < NN)
        *(bf16x8*)(Yb + (size_t)rowg * 512 + wid * 128 + lr * 8) = v;
    }
  }
}

// One wave per node: out[n] = deg[n]*(Y1b[n]+b) + sum_{CSR} Y2b[j]
// Yb row = 512 bf16: cols 0..255 = Y1, 256..511 = Y2. All 512B reads coalesced.
__global__ __launch_bounds__(256) void k_epi(
    const unsigned short* __restrict__ Yb, const int* __restrict__ offs,
    const int* __restrict__ deg, const int* __restrict__ edst,
    const float* __restrict__ bias, float* __restrict__ out) {
  int wid = threadIdx.x >> 6;
  int lane = threadIdx.x & 63;
  int n = blockIdx.x * 4 + wid;
  if (n >= NN) return;
  int o = offs[n];
  int c = deg[n];
  f32x4 acc = {0.f, 0.f, 0.f, 0.f};
  for (int e = 0; e < c; ++e) {
    int j = edst[o + e];
    u16x4 v = *(const u16x4*)(Yb + (size_t)j * 512 + 256 + lane * 4);
    #pragma unroll
    for (int i = 0; i < 4; ++i)
      acc[i] += __builtin_bit_cast(float, ((unsigned int)v[i]) << 16);
  }
  u16x4 y1 = *(const u16x4*)(Yb + (size_t)n * 512 + lane * 4);
  f32x4 bv = *(const f32x4*)(bias + lane * 4);
  float dg = (float)c;
  f32x4 res;
  #pragma unroll
  for (int i = 0; i < 4; ++i)
    res[i] = dg * (__builtin_bit_cast(float, ((unsigned int)y1[i]) << 16) + bv[i]) + acc[i];
  *((f32x4*)out + (size_t)n * 64 + lane) = res;
}

extern "C" void kernel_launch(void* const* d_in, const int* in_sizes, int n_in,
                              void* d_out, int out_size, void* d_ws, size_t ws_size,
                              hipStream_t stream) {
  const float* x = (const float*)d_in[0];
  const float* W = (const float*)d_in[1];
  const float* b = (const float*)d_in[2];
  const int* Ai = (const int*)d_in[3];
  const int* Aj = (const int*)d_in[4];
  float* out = (float*)d_out;

  int* ip = (int*)d_ws;
  int* deg    = ip;            // 50048 (zeroed via memset, padded)
  int* incl   = ip + 50048;
  int* offs   = ip + 100096;
  int* cursor = ip + 150144;
  int* bsum   = ip + 200192;   // 256
  int* edst   = ip + 200448;   // 312576
  unsigned short* WbP = (unsigned short*)(ip + 513024);   // 131072 bf16 = 256KB
  unsigned short* Yb  = (unsigned short*)(ip + 578560);   // 50048*512 bf16 = 51.2MB

  hipMemsetAsync(deg, 0, 50048 * sizeof(int), stream);
  k_hist<<<1221, 256, 0, stream>>>(Ai, deg);
  k_scan1<<<196, 256, 0, stream>>>(deg, incl, bsum);
  k_scan2<<<1, 256, 0, stream>>>(bsum);
  k_scan3<<<196, 256, 0, stream>>>(incl, deg, bsum, offs, cursor);
  k_scatter<<<1221, 256, 0, stream>>>(Ai, Aj, cursor, edst);
  k_wconv<<<64, 256, 0, stream>>>(W, WbP);
  k_gemm<<<782, 256, 0, stream>>>(x, WbP, Yb);
  k_epi<<<12500, 256, 0, stream>>>(Yb, offs, deg, edst, b, out);
}

// Round 6
// 117.950 us; speedup vs baseline: 1.7444x; 1.0702x over previous
//
#include <hip/hip_runtime.h>
#include <hip/hip_bf16.h>

#define NN 50000
#define NE 312500
#define FIN 256
#define MPAD 50048   // 1564*32

typedef __attribute__((ext_vector_type(4))) float f32x4;
typedef __attribute__((ext_vector_type(8))) short bf16x8;
typedef __attribute__((ext_vector_type(4))) unsigned short u16x4;

__device__ __forceinline__ float bf2f(unsigned short u) {
  return __builtin_bit_cast(float, ((unsigned int)u) << 16);
}

__global__ void k_hist(const int* __restrict__ Ai, int* __restrict__ deg) {
  int e = blockIdx.x * 256 + threadIdx.x;
  if (e < NE) atomicAdd(&deg[Ai[e]], 1);
}

__global__ void k_scan1(const int* __restrict__ deg, int* __restrict__ incl,
                        int* __restrict__ bsum) {
  __shared__ int sm[256];
  int i = blockIdx.x * 256 + threadIdx.x;
  int v = (i < NN) ? deg[i] : 0;
  sm[threadIdx.x] = v;
  __syncthreads();
  for (int s = 1; s < 256; s <<= 1) {
    int t = (threadIdx.x >= (unsigned)s) ? sm[threadIdx.x - s] : 0;
    __syncthreads();
    sm[threadIdx.x] += t;
    __syncthreads();
  }
  if (i < NN) incl[i] = sm[threadIdx.x];
  if (threadIdx.x == 255) bsum[blockIdx.x] = sm[255];
}

__global__ void k_scan2(int* __restrict__ bsum) {
  __shared__ int sm[256];
  int v = (threadIdx.x < 196) ? bsum[threadIdx.x] : 0;
  sm[threadIdx.x] = v;
  __syncthreads();
  for (int s = 1; s < 256; s <<= 1) {
    int t = (threadIdx.x >= (unsigned)s) ? sm[threadIdx.x - s] : 0;
    __syncthreads();
    sm[threadIdx.x] += t;
    __syncthreads();
  }
  if (threadIdx.x < 196) bsum[threadIdx.x] = sm[threadIdx.x] - v;
}

__global__ void k_scan3(const int* __restrict__ incl, const int* __restrict__ deg,
                        const int* __restrict__ bsum, int* __restrict__ offs,
                        int* __restrict__ cursor) {
  int i = blockIdx.x * 256 + threadIdx.x;
  if (i < NN) {
    int o = incl[i] - deg[i] + bsum[blockIdx.x];
    offs[i] = o;
    cursor[i] = o;
  }
}

__global__ void k_scatter(const int* __restrict__ Ai, const int* __restrict__ Aj,
                          int* __restrict__ cursor, int* __restrict__ edst) {
  int e = blockIdx.x * 256 + threadIdx.x;
  if (e < NE) {
    int p = atomicAdd(&cursor[Ai[e]], 1);
    edst[p] = Aj[e];
  }
}

__device__ __forceinline__ bf16x8 cvt8(const float* p) {
  f32x4 a = *(const f32x4*)p;
  f32x4 c = *(const f32x4*)(p + 4);
  bf16x8 r;
  #pragma unroll
  for (int i = 0; i < 4; ++i) {
    r[i]     = (short)__builtin_bit_cast(unsigned short, __float2bfloat16(a[i]));
    r[i + 4] = (short)__builtin_bit_cast(unsigned short, __float2bfloat16(c[i]));
  }
  return r;
}

// Pack Wcat[o][k] (o<256 -> W1 row o; o>=256 -> W2 row o-256) into B-fragment
// order: chunk c = (o/16)*8 + kk; lane l=(lk<<4)|lr holds 8 bf16 of
// (col o16*16+lr, k kk*32+lk*8). 1KB contiguous per chunk.
__global__ __launch_bounds__(256) void k_wconv(const float* __restrict__ W,
                                               unsigned short* __restrict__ WbP) {
  int lane = threadIdx.x & 63, wid = threadIdx.x >> 6;
  int c = blockIdx.x * 4 + wid;           // 256 chunks
  int o16 = c >> 3, kk = c & 7;
  int lr = lane & 15, lk = lane >> 4;
  int o = o16 * 16 + lr;
  int k = kk * 32 + lk * 8;
  const float* src = (o < 256) ? (W + (size_t)o * 512 + k)
                               : (W + (size_t)(o - 256) * 512 + 256 + k);
  *(bf16x8*)(WbP + (size_t)c * 512 + lane * 8) = cvt8(src);
}

// Fused GEMM: Yb[row][0..511] = bf16( x[row] @ [W1|W2]^T ).
// Block: 32 rows x 512 cols; 4 waves, wave w = cols w*128..+127 (8 col16 frags).
// x staged fp32->bf16 A-fragments in LDS (16KB); reg ping-pong over 8 K-steps;
// epilogue transposes 16x128 chunks through XOR-swizzled LDS -> 16B stores.
__global__ __launch_bounds__(256, 2) void k_gemm(
    const float* __restrict__ x, const unsigned short* __restrict__ WbP,
    unsigned short* __restrict__ Yb) {
  __shared__ unsigned short Alds[16384];   // 32 KB (stage uses 16KB; epilogue 32KB)
  const int tid = threadIdx.x;
  const int lane = tid & 63, wid = tid >> 6;
  const int lr = lane & 15, lk = lane >> 4;
  const int n0 = blockIdx.x * 32;

  // ---- stage A: 32 rows x 256 k, fragment order (16 chunks x 512 bf16) ----
  #pragma unroll
  for (int it = 0; it < 4; ++it) {
    int i = it * 256 + tid;          // 0..1023
    int row = i >> 5, seg = i & 31;  // seg = 8-float group
    int g = n0 + row;
    bf16x8 v = {0, 0, 0, 0, 0, 0, 0, 0};
    if (g < NN) v = cvt8(x + (size_t)g * FIN + seg * 8);
    int kk = seg >> 2, lkk = seg & 3;
    int chunk = (row >> 4) * 8 + kk;
    *(bf16x8*)(Alds + chunk * 512 + (lkk * 16 + (row & 15)) * 8) = v;
  }
  __syncthreads();

  f32x4 acc[2][8];
  #pragma unroll
  for (int m = 0; m < 2; ++m)
    #pragma unroll
    for (int n = 0; n < 8; ++n) acc[m][n] = (f32x4){0.f, 0.f, 0.f, 0.f};

  bf16x8 af[2][2], bfr[2][8];
  #pragma unroll
  for (int m = 0; m < 2; ++m)
    af[0][m] = *(const bf16x8*)(Alds + (m * 8 + 0) * 512 + lane * 8);
  #pragma unroll
  for (int n = 0; n < 8; ++n)
    bfr[0][n] = *(const bf16x8*)(WbP + ((size_t)((wid * 8 + n) * 8 + 0)) * 512 + lane * 8);

  #pragma unroll
  for (int kk = 0; kk < 8; ++kk) {
    const int cur = kk & 1, nxt = cur ^ 1;
    if (kk < 7) {
      #pragma unroll
      for (int m = 0; m < 2; ++m)
        af[nxt][m] = *(const bf16x8*)(Alds + (m * 8 + kk + 1) * 512 + lane * 8);
      #pragma unroll
      for (int n = 0; n < 8; ++n)
        bfr[nxt][n] = *(const bf16x8*)(WbP + ((size_t)((wid * 8 + n) * 8 + kk + 1)) * 512 + lane * 8);
    }
    #pragma unroll
    for (int m = 0; m < 2; ++m)
      #pragma unroll
      for (int n = 0; n < 8; ++n)
        acc[m][n] = __builtin_amdgcn_mfma_f32_16x16x32_bf16(af[cur][m], bfr[cur][n], acc[m][n], 0, 0, 0);
  }

  __syncthreads();   // A-tile done; LDS reused per-wave below

  // ---- epilogue: per m-chunk (16 rows x 128 cols), LDS transpose, 16B stores ----
  #pragma unroll
  for (int m = 0; m < 2; ++m) {
    unsigned short* R = Alds + wid * 4096 + (m & 1) * 2048;
    #pragma unroll
    for (int n = 0; n < 8; ++n) {
      #pragma unroll
      for (int r = 0; r < 4; ++r) {
        int col = n * 16 + lr;
        int word = (lk * 4 + r) * 64 + (((unsigned)col >> 1) ^ (lk << 3));
        R[word * 2 + (col & 1)] =
            __builtin_bit_cast(unsigned short, __float2bfloat16(acc[m][n][r]));
      }
    }
    #pragma unroll
    for (int p = 0; p < 4; ++p) {
      int row_l = p * 4 + lk;
      bf16x8 v = *(const bf16x8*)(R + (row_l * 64 + ((lr * 4) ^ (p << 3))) * 2);
      int rowg = n0 + m * 16 + row_l;
      if (rowg < NN)
        *(bf16x8*)(Yb + (size_t)rowg * 512 + wid * 128 + lr * 8) = v;
    }
  }
}

// One wave per node: out[n] = deg[n]*(Y1b[n]+b) + sum_{CSR} Y2b[j]
// Unrolled 4-wide: 4 independent 512B row loads in flight (MLP=4).
__global__ __launch_bounds__(256) void k_epi(
    const unsigned short* __restrict__ Yb, const int* __restrict__ offs,
    const int* __restrict__ deg, const int* __restrict__ edst,
    const float* __restrict__ bias, float* __restrict__ out) {
  int wid = threadIdx.x >> 6;
  int lane = threadIdx.x & 63;
  int n = blockIdx.x * 4 + wid;
  if (n >= NN) return;
  int o = offs[n];
  int c = deg[n];
  const unsigned short* Y2 = Yb + 256 + (size_t)lane * 4;
  f32x4 a0 = {0.f,0.f,0.f,0.f}, a1 = a0, a2 = a0, a3 = a0;
  int e = 0;
  for (; e + 4 <= c; e += 4) {
    int j0 = edst[o + e], j1 = edst[o + e + 1], j2 = edst[o + e + 2], j3 = edst[o + e + 3];
    u16x4 v0 = *(const u16x4*)(Y2 + (size_t)j0 * 512);
    u16x4 v1 = *(const u16x4*)(Y2 + (size_t)j1 * 512);
    u16x4 v2 = *(const u16x4*)(Y2 + (size_t)j2 * 512);
    u16x4 v3 = *(const u16x4*)(Y2 + (size_t)j3 * 512);
    #pragma unroll
    for (int i = 0; i < 4; ++i) {
      a0[i] += bf2f(v0[i]); a1[i] += bf2f(v1[i]);
      a2[i] += bf2f(v2[i]); a3[i] += bf2f(v3[i]);
    }
  }
  if (e + 2 <= c) {
    int j0 = edst[o + e], j1 = edst[o + e + 1];
    u16x4 v0 = *(const u16x4*)(Y2 + (size_t)j0 * 512);
    u16x4 v1 = *(const u16x4*)(Y2 + (size_t)j1 * 512);
    #pragma unroll
    for (int i = 0; i < 4; ++i) { a0[i] += bf2f(v0[i]); a1[i] += bf2f(v1[i]); }
    e += 2;
  }
  if (e < c) {
    int j0 = edst[o + e];
    u16x4 v0 = *(const u16x4*)(Y2 + (size_t)j0 * 512);
    #pragma unroll
    for (int i = 0; i < 4; ++i) a0[i] += bf2f(v0[i]);
  }
  u16x4 y1 = *(const u16x4*)(Yb + (size_t)n * 512 + lane * 4);
  f32x4 bv = *(const f32x4*)(bias + lane * 4);
  float dg = (float)c;
  f32x4 res;
  #pragma unroll
  for (int i = 0; i < 4; ++i)
    res[i] = dg * (bf2f(y1[i]) + bv[i]) + ((a0[i] + a1[i]) + (a2[i] + a3[i]));
  __builtin_nontemporal_store(res, (f32x4*)out + (size_t)n * 64 + lane);
}

extern "C" void kernel_launch(void* const* d_in, const int* in_sizes, int n_in,
                              void* d_out, int out_size, void* d_ws, size_t ws_size,
                              hipStream_t stream) {
  const float* x = (const float*)d_in[0];
  const float* W = (const float*)d_in[1];
  const float* b = (const float*)d_in[2];
  const int* Ai = (const int*)d_in[3];
  const int* Aj = (const int*)d_in[4];
  float* out = (float*)d_out;

  int* ip = (int*)d_ws;
  int* deg    = ip;            // 50048 (zeroed via memset, padded)
  int* incl   = ip + 50048;
  int* offs   = ip + 100096;
  int* cursor = ip + 150144;
  int* bsum   = ip + 200192;   // 256
  int* edst   = ip + 200448;   // 312576
  unsigned short* WbP = (unsigned short*)(ip + 513024);   // 131072 bf16 = 256KB
  unsigned short* Yb  = (unsigned short*)(ip + 578560);   // 50048*512 bf16 = 51.2MB

  hipMemsetAsync(deg, 0, 50048 * sizeof(int), stream);
  k_hist<<<1221, 256, 0, stream>>>(Ai, deg);
  k_scan1<<<196, 256, 0, stream>>>(deg, incl, bsum);
  k_scan2<<<1, 256, 0, stream>>>(bsum);
  k_scan3<<<196, 256, 0, stream>>>(incl, deg, bsum, offs, cursor);
  k_scatter<<<1221, 256, 0, stream>>>(Ai, Aj, cursor, edst);
  k_wconv<<<64, 256, 0, stream>>>(W, WbP);
  k_gemm<<<1564, 256, 0, stream>>>(x, WbP, Yb);
  k_epi<<<12500, 256, 0, stream>>>(Yb, offs, deg, edst, b, out);
}